// Round 1
// 3849.218 us; speedup vs baseline: 1.6089x; 1.6089x over previous
//
#include <hip/hip_runtime.h>
#include <math.h>

#define LSEQ   2048
#define DMODEL 1024
#define DINNER 2048
#define DSTATE 16
#define DTRANK 64
#define NVOCAB 50264

typedef __bf16 bf16x8 __attribute__((ext_vector_type(8)));
typedef float  f32x4  __attribute__((ext_vector_type(4)));

__device__ __forceinline__ float sp_softplus(float x) {
    return fmaxf(x, 0.f) + log1pf(__expf(-fabsf(x)));
}
__device__ __forceinline__ float silu_f(float x) {
    return x / (1.f + __expf(-x));
}

// split fp32 into bf16 hi (truncate) + bf16 lo (truncate of residual), store to LDS
__device__ __forceinline__ void split_store4(ushort* ph, ushort* pl, float4 v) {
    uint bx = __float_as_uint(v.x), by = __float_as_uint(v.y),
         bz = __float_as_uint(v.z), bw = __float_as_uint(v.w);
    ushort4 h = make_ushort4((ushort)(bx >> 16), (ushort)(by >> 16),
                             (ushort)(bz >> 16), (ushort)(bw >> 16));
    float lx = v.x - __uint_as_float(bx & 0xFFFF0000u);
    float ly = v.y - __uint_as_float(by & 0xFFFF0000u);
    float lz = v.z - __uint_as_float(bz & 0xFFFF0000u);
    float lw = v.w - __uint_as_float(bw & 0xFFFF0000u);
    ushort4 l = make_ushort4((ushort)(__float_as_uint(lx) >> 16),
                             (ushort)(__float_as_uint(ly) >> 16),
                             (ushort)(__float_as_uint(lz) >> 16),
                             (ushort)(__float_as_uint(lw) >> 16));
    *(ushort4*)ph = h;
    *(ushort4*)pl = l;
}

// ---------------- embedding gather ----------------
__global__ void embed_k(const int* __restrict__ ids, const float* __restrict__ emb,
                        float* __restrict__ x) {
    int l = blockIdx.x;
    int id = ids[l];
    const float4* src = (const float4*)(emb + (size_t)id * DMODEL);
    float4* dst = (float4*)(x + (size_t)l * DMODEL);
    dst[threadIdx.x] = src[threadIdx.x];   // 256 threads * float4 = 1024 floats
}

// ---------------- RMSNorm (one block per row, 1024 elems) ----------------
__global__ void rmsnorm_k(const float* __restrict__ x, const float* __restrict__ w,
                          float* __restrict__ out) {
    int l = blockIdx.x;
    const float4* xr = (const float4*)(x + (size_t)l * DMODEL);
    float4 v = xr[threadIdx.x];
    float ss = v.x*v.x + v.y*v.y + v.z*v.z + v.w*v.w;
    for (int off = 32; off > 0; off >>= 1) ss += __shfl_down(ss, off, 64);
    __shared__ float sred[4];
    int wid = threadIdx.x >> 6;
    if ((threadIdx.x & 63) == 0) sred[wid] = ss;
    __syncthreads();
    float tot = sred[0] + sred[1] + sred[2] + sred[3];
    float scale = rsqrtf(tot * (1.0f / DMODEL) + 1e-5f);
    float4 wv = ((const float4*)w)[threadIdx.x];
    float4 o;
    o.x = v.x * scale * wv.x; o.y = v.y * scale * wv.y;
    o.z = v.z * scale * wv.z; o.w = v.w * scale * wv.w;
    ((float4*)(out + (size_t)l * DMODEL))[threadIdx.x] = o;
}

// ---------------- causal depthwise conv (k=4) + silu ----------------
__global__ void conv_silu_k(const float* __restrict__ XR, const float* __restrict__ w,
                            const float* __restrict__ b, float* __restrict__ out) {
    int idx = blockIdx.x * blockDim.x + threadIdx.x;
    int d = idx & (DINNER - 1);
    int l = idx >> 11;
    float4 wv = *(const float4*)(w + (size_t)d * 4);
    float acc = b[d];
    const float* col = XR + d;
    if (l >= 3) {
        acc += wv.x * col[(size_t)(l-3) * (2*DINNER)];
        acc += wv.y * col[(size_t)(l-2) * (2*DINNER)];
        acc += wv.z * col[(size_t)(l-1) * (2*DINNER)];
    } else {
        if (l-3 >= 0) acc += wv.x * col[(size_t)(l-3) * (2*DINNER)];
        if (l-2 >= 0) acc += wv.y * col[(size_t)(l-2) * (2*DINNER)];
        if (l-1 >= 0) acc += wv.z * col[(size_t)(l-1) * (2*DINNER)];
    }
    acc += wv.w * col[(size_t)l * (2*DINNER)];
    out[(size_t)l * DINNER + d] = silu_f(acc);
}

// ---------------- fp32 GEMM (kept for small K / small N cases) ----------------
// EPI: 0 = plain store, 2 = softplus(acc + E[n]) (bias)
template<int EPI, bool BNC>
__global__ __launch_bounds__(256) void gemm_bt_k(
    const float* __restrict__ A, const float* __restrict__ B, float* __restrict__ C,
    int M, int N, int K, int lda, int ldb, int ldc, const float* __restrict__ E)
{
    __shared__ float As[16][68];
    __shared__ float Bs[16][68];
    int m0 = blockIdx.y * 64;
    int n0 = blockIdx.x * 64;
    int t = threadIdx.x;
    int tx = t & 15, ty = t >> 4;
    int lrow = t >> 2;
    int lc = (t & 3) * 4;
    float acc[4][4] = {};

    for (int k0 = 0; k0 < K; k0 += 16) {
        float4 a4 = *(const float4*)(A + (size_t)(m0 + lrow) * lda + k0 + lc);
        As[lc + 0][lrow] = a4.x; As[lc + 1][lrow] = a4.y;
        As[lc + 2][lrow] = a4.z; As[lc + 3][lrow] = a4.w;
        float4 b4;
        if (BNC && (n0 + lrow >= N)) b4 = make_float4(0.f, 0.f, 0.f, 0.f);
        else b4 = *(const float4*)(B + (size_t)(n0 + lrow) * ldb + k0 + lc);
        Bs[lc + 0][lrow] = b4.x; Bs[lc + 1][lrow] = b4.y;
        Bs[lc + 2][lrow] = b4.z; Bs[lc + 3][lrow] = b4.w;
        __syncthreads();
#pragma unroll
        for (int k = 0; k < 16; ++k) {
            float4 av = *(const float4*)(&As[k][ty * 4]);
            float4 bv = *(const float4*)(&Bs[k][tx * 4]);
            acc[0][0] += av.x * bv.x; acc[0][1] += av.x * bv.y;
            acc[0][2] += av.x * bv.z; acc[0][3] += av.x * bv.w;
            acc[1][0] += av.y * bv.x; acc[1][1] += av.y * bv.y;
            acc[1][2] += av.y * bv.z; acc[1][3] += av.y * bv.w;
            acc[2][0] += av.z * bv.x; acc[2][1] += av.z * bv.y;
            acc[2][2] += av.z * bv.z; acc[2][3] += av.z * bv.w;
            acc[3][0] += av.w * bv.x; acc[3][1] += av.w * bv.y;
            acc[3][2] += av.w * bv.z; acc[3][3] += av.w * bv.w;
        }
        __syncthreads();
    }

    int n = n0 + tx * 4;
    if (BNC && n >= N) return;
#pragma unroll
    for (int i = 0; i < 4; ++i) {
        int m = m0 + ty * 4 + i;
        float4 r;
        r.x = acc[i][0]; r.y = acc[i][1]; r.z = acc[i][2]; r.w = acc[i][3];
        if (EPI == 2) {
            float4 bb = *(const float4*)(E + n);
            r.x = sp_softplus(r.x + bb.x); r.y = sp_softplus(r.y + bb.y);
            r.z = sp_softplus(r.z + bb.z); r.w = sp_softplus(r.w + bb.w);
        }
        *(float4*)(C + (size_t)m * ldc + n) = r;
    }
}

// ---------------- split-bf16 MFMA GEMM: C[M,N] = A[M,K] @ B[N,K]^T ----------------
// fp32 inputs split on the fly into bf16 hi/lo; 3 MFMA products (hh + lh + hl)
// give ~2^-14 relative accuracy. Tile 128x128, BK=32, 4 waves each own a 64x64
// quadrant of 16 (16x16) fragments. EPI: 0 = store, 1 = store + E (residual).
// Requires: M % 128 == 0, K % 32 == 0. N ragged handled when BNC.
template<int EPI, bool BNC>
__global__ __launch_bounds__(256, 3) void gemm_mfma_k(
    const float* __restrict__ A, const float* __restrict__ B, float* __restrict__ C,
    int M, int N, int K, int lda, int ldb, int ldc, const float* __restrict__ E)
{
    // +8 ushort pad (stride 40 = 80B): fragment ds_read_b128 lands 2 lanes/bank (free),
    // and 80B keeps 16B alignment for bf16x8 reads.
    __shared__ ushort Ah[128][40];
    __shared__ ushort Al[128][40];
    __shared__ ushort Bh[128][40];
    __shared__ ushort Bl[128][40];

    const int t    = threadIdx.x;
    const int lane = t & 63;
    const int wave = t >> 6;
    const int wm   = (wave >> 1) * 64;     // wave's quadrant row offset
    const int wn   = (wave & 1) * 64;      // wave's quadrant col offset
    const int m0   = blockIdx.y * 128;
    const int n0   = blockIdx.x * 128;
    const int lrow = t >> 3;               // 0..31 staging row
    const int lk   = (t & 7) * 4;          // staging k (float4 granule)
    const int fr   = lane & 15;            // fragment row (A) / col (B)
    const int kg   = (lane >> 4) * 8;      // fragment k-group (8 contiguous)

    const f32x4 zero = {0.f, 0.f, 0.f, 0.f};
    f32x4 acc[4][4];
#pragma unroll
    for (int i = 0; i < 4; ++i)
#pragma unroll
        for (int j = 0; j < 4; ++j) acc[i][j] = zero;

    for (int k0 = 0; k0 < K; k0 += 32) {
#pragma unroll
        for (int i = 0; i < 4; ++i) {
            int r = lrow + i * 32;
            float4 a4 = *(const float4*)(A + (size_t)(m0 + r) * lda + k0 + lk);
            split_store4(&Ah[r][lk], &Al[r][lk], a4);
            float4 b4;
            if (BNC && (n0 + r >= N)) b4 = make_float4(0.f, 0.f, 0.f, 0.f);
            else b4 = *(const float4*)(B + (size_t)(n0 + r) * ldb + k0 + lk);
            split_store4(&Bh[r][lk], &Bl[r][lk], b4);
        }
        __syncthreads();

        bf16x8 ah[4], al[4];
#pragma unroll
        for (int mt = 0; mt < 4; ++mt) {
            ah[mt] = *(const bf16x8*)&Ah[wm + mt * 16 + fr][kg];
            al[mt] = *(const bf16x8*)&Al[wm + mt * 16 + fr][kg];
        }
#pragma unroll
        for (int nt = 0; nt < 4; ++nt) {
            bf16x8 bh = *(const bf16x8*)&Bh[wn + nt * 16 + fr][kg];
            bf16x8 bl = *(const bf16x8*)&Bl[wn + nt * 16 + fr][kg];
#pragma unroll
            for (int mt = 0; mt < 4; ++mt) {
                acc[mt][nt] = __builtin_amdgcn_mfma_f32_16x16x32_bf16(ah[mt], bh, acc[mt][nt], 0, 0, 0);
                acc[mt][nt] = __builtin_amdgcn_mfma_f32_16x16x32_bf16(al[mt], bh, acc[mt][nt], 0, 0, 0);
                acc[mt][nt] = __builtin_amdgcn_mfma_f32_16x16x32_bf16(ah[mt], bl, acc[mt][nt], 0, 0, 0);
            }
        }
        __syncthreads();
    }

    // epilogue: C/D layout col = lane&15, row = (lane>>4)*4 + reg
    const int rq = (lane >> 4) * 4;
#pragma unroll
    for (int nt = 0; nt < 4; ++nt) {
        int n = n0 + wn + nt * 16 + fr;
        if (BNC && n >= N) continue;
#pragma unroll
        for (int mt = 0; mt < 4; ++mt) {
            int mb = m0 + wm + mt * 16 + rq;
#pragma unroll
            for (int r = 0; r < 4; ++r) {
                float v = acc[mt][nt][r];
                if (EPI == 1) v += E[(size_t)(mb + r) * ldc + n];
                C[(size_t)(mb + r) * ldc + n] = v;
            }
        }
    }
}

// ---------------- selective scan ----------------
__global__ __launch_bounds__(256) void scan_k(
    const float* __restrict__ delta, const float* __restrict__ u,
    const float* __restrict__ xdbl, const float* __restrict__ A_log,
    const float* __restrict__ Dp, const float* __restrict__ XR,
    float* __restrict__ yz)
{
    const int CH = 64;
    int d0 = blockIdx.x * 16;
    int t = threadIdx.x;
    int ci = t >> 4;
    int n  = t & 15;
    int d  = d0 + ci;
    float Av = -__expf(A_log[(size_t)d * DSTATE + n]);
    float Dv = Dp[d];
    float h = 0.f;

    __shared__ float sdel[CH][16];
    __shared__ float su[CH][16];
    __shared__ float sres[CH][16];
    __shared__ float sBC[CH][32];

    for (int l0 = 0; l0 < LSEQ; l0 += CH) {
        {
            int r = t >> 2, c = (t & 3) * 4;
            *(float4*)&sdel[r][c] = *(const float4*)(delta + (size_t)(l0 + r) * DINNER + d0 + c);
            *(float4*)&su[r][c]   = *(const float4*)(u     + (size_t)(l0 + r) * DINNER + d0 + c);
            *(float4*)&sres[r][c] = *(const float4*)(XR + (size_t)(l0 + r) * (2*DINNER) + DINNER + d0 + c);
        }
        for (int q = t; q < CH * 8; q += 256) {
            int r = q >> 3, c = (q & 7) * 4;
            *(float4*)&sBC[r][c] = *(const float4*)(xdbl + (size_t)(l0 + r) * 96 + DTRANK + c);
        }
        __syncthreads();
#pragma unroll 4
        for (int r = 0; r < CH; ++r) {
            float dl = sdel[r][ci];
            float uv = su[r][ci];
            float Bv = sBC[r][n];
            float Cv = sBC[r][16 + n];
            float dA = __expf(dl * Av);
            h = dA * h + dl * uv * Bv;
            float p = h * Cv;
            p += __shfl_xor(p, 1, 64);
            p += __shfl_xor(p, 2, 64);
            p += __shfl_xor(p, 4, 64);
            p += __shfl_xor(p, 8, 64);
            if (n == 0) {
                float y = p + uv * Dv;
                yz[(size_t)(l0 + r) * DINNER + d] = y * silu_f(sres[r][ci]);
            }
        }
        __syncthreads();
    }
}

extern "C" void kernel_launch(void* const* d_in, const int* in_sizes, int n_in,
                              void* d_out, int out_size, void* d_ws, size_t ws_size,
                              hipStream_t stream) {
    const int*   ids    = (const int*)  d_in[0];
    const float* emb    = (const float*)d_in[1];
    const float* in_w   = (const float*)d_in[2];   // [2,4096,1024]
    const float* conv_w = (const float*)d_in[3];   // [2,2048,1,4]
    const float* conv_b = (const float*)d_in[4];   // [2,2048]
    const float* xp_w   = (const float*)d_in[5];   // [2,96,2048]
    const float* dt_w   = (const float*)d_in[6];   // [2,2048,64]
    const float* dt_b   = (const float*)d_in[7];   // [2,2048]
    const float* A_log  = (const float*)d_in[8];   // [2,2048,16]
    const float* Dp     = (const float*)d_in[9];   // [2,2048]
    const float* out_w  = (const float*)d_in[10];  // [2,1024,2048]
    const float* nw     = (const float*)d_in[11];  // [2,1024]
    const float* nfw    = (const float*)d_in[12];  // [1024]
    float* out = (float*)d_out;

    float* ws    = (float*)d_ws;
    float* x     = ws;                    // [L,1024]
    float* h     = x     + (size_t)LSEQ * DMODEL;
    float* XR    = h     + (size_t)LSEQ * DMODEL;        // [L,4096]
    float* xconv = XR    + (size_t)LSEQ * 2 * DINNER;    // [L,2048]
    float* xdbl  = xconv + (size_t)LSEQ * DINNER;        // [L,96]
    float* delta = xdbl  + (size_t)LSEQ * 96;            // [L,2048]
    float* yz    = delta + (size_t)LSEQ * DINNER;        // [L,2048]

    embed_k<<<LSEQ, 256, 0, stream>>>(ids, emb, x);

    for (int i = 0; i < 2; ++i) {
        rmsnorm_k<<<LSEQ, 256, 0, stream>>>(x, nw + (size_t)i * DMODEL, h);
        // in_proj: [L,1024] @ [4096,1024]^T -> XR [L,4096]   (MFMA split-bf16)
        gemm_mfma_k<0, false><<<dim3(4096/128, LSEQ/128), 256, 0, stream>>>(
            h, in_w + (size_t)i * 2*DINNER * DMODEL, XR,
            LSEQ, 2*DINNER, DMODEL, DMODEL, DMODEL, 2*DINNER, nullptr);
        conv_silu_k<<<(LSEQ * DINNER) / 256, 256, 0, stream>>>(
            XR, conv_w + (size_t)i * DINNER * 4, conv_b + (size_t)i * DINNER, xconv);
        // x_proj: [L,2048] @ [96,2048]^T -> xdbl [L,96]   (fp32 path, tiny N)
        gemm_bt_k<0, true><<<dim3(2, LSEQ/64), 256, 0, stream>>>(
            xconv, xp_w + (size_t)i * 96 * DINNER, xdbl,
            LSEQ, 96, DINNER, DINNER, DINNER, 96, nullptr);
        // dt_proj + softplus: [L,64] @ [2048,64]^T -> delta [L,2048]   (fp32 path, K=64)
        gemm_bt_k<2, false><<<dim3(DINNER/64, LSEQ/64), 256, 0, stream>>>(
            xdbl, dt_w + (size_t)i * DINNER * DTRANK, delta,
            LSEQ, DINNER, DTRANK, 96, DTRANK, DINNER, dt_b + (size_t)i * DINNER);
        scan_k<<<DINNER/16, 256, 0, stream>>>(
            delta, xconv, xdbl, A_log + (size_t)i * DINNER * DSTATE,
            Dp + (size_t)i * DINNER, XR, yz);
        // out_proj + residual: [L,2048] @ [1024,2048]^T + x -> x   (MFMA split-bf16)
        gemm_mfma_k<1, false><<<dim3(DMODEL/128, LSEQ/128), 256, 0, stream>>>(
            yz, out_w + (size_t)i * DMODEL * DINNER, x,
            LSEQ, DMODEL, DINNER, DINNER, DINNER, DMODEL, x);
    }

    rmsnorm_k<<<LSEQ, 256, 0, stream>>>(x, nfw, h);
    // logits: [L,1024] @ [50264,1024]^T -> out [L,50264]   (MFMA split-bf16)
    gemm_mfma_k<0, true><<<dim3((NVOCAB + 127) / 128, LSEQ/128), 256, 0, stream>>>(
        h, emb, out, LSEQ, NVOCAB, DMODEL, DMODEL, DMODEL, NVOCAB, nullptr);
}

// Round 4
// 2246.976 us; speedup vs baseline: 2.7561x; 1.7131x over previous
//
#include <hip/hip_runtime.h>
#include <math.h>

#define LSEQ   2048
#define DMODEL 1024
#define DINNER 2048
#define DSTATE 16
#define DTRANK 64
#define NVOCAB 50264
#define NVPAD  50304   // padded to multiple of 128 for logits GEMM tiles

typedef __bf16 bf16x8 __attribute__((ext_vector_type(8)));
typedef float  f32x4  __attribute__((ext_vector_type(4)));

__device__ __forceinline__ float sp_softplus(float x) {
    return fmaxf(x, 0.f) + log1pf(__expf(-fabsf(x)));
}
__device__ __forceinline__ float silu_f(float x) {
    return x / (1.f + __expf(-x));
}

// ---- RNE bf16 split: x ~= hi + lo ----
__device__ __forceinline__ ushort bf16_rne(float x) {
    uint u = __float_as_uint(x);
    return (ushort)((u + 0x7FFFu + ((u >> 16) & 1u)) >> 16);
}
__device__ __forceinline__ void split_hl(float x, ushort& hi, ushort& lo) {
    hi = bf16_rne(x);
    float fh = __uint_as_float(((uint)hi) << 16);
    lo = bf16_rne(x - fh);
}

// truncation split (fallback path, matches round-1 behavior)
__device__ __forceinline__ void split_store4(ushort* ph, ushort* pl, float4 v) {
    uint bx = __float_as_uint(v.x), by = __float_as_uint(v.y),
         bz = __float_as_uint(v.z), bw = __float_as_uint(v.w);
    ushort4 h = make_ushort4((ushort)(bx >> 16), (ushort)(by >> 16),
                             (ushort)(bz >> 16), (ushort)(bw >> 16));
    float lx = v.x - __uint_as_float(bx & 0xFFFF0000u);
    float ly = v.y - __uint_as_float(by & 0xFFFF0000u);
    float lz = v.z - __uint_as_float(bz & 0xFFFF0000u);
    float lw = v.w - __uint_as_float(bw & 0xFFFF0000u);
    ushort4 l = make_ushort4((ushort)(__float_as_uint(lx) >> 16),
                             (ushort)(__float_as_uint(ly) >> 16),
                             (ushort)(__float_as_uint(lz) >> 16),
                             (ushort)(__float_as_uint(lw) >> 16));
    *(ushort4*)ph = h;
    *(ushort4*)pl = l;
}

// ---------------- embedding gather ----------------
__global__ void embed_k(const int* __restrict__ ids, const float* __restrict__ emb,
                        float* __restrict__ x) {
    int l = blockIdx.x;
    int id = ids[l];
    const float4* src = (const float4*)(emb + (size_t)id * DMODEL);
    float4* dst = (float4*)(x + (size_t)l * DMODEL);
    dst[threadIdx.x] = src[threadIdx.x];
}

// ---------------- fp32 -> (hi,lo) bf16 plane split, zero-padded rows ----
__global__ void split_rows_k(const float* __restrict__ src, ushort* __restrict__ ph,
                             ushort* __restrict__ pl, int rows, int cols) {
    int row = blockIdx.x;
    for (int c = threadIdx.x * 4; c < cols; c += blockDim.x * 4) {
        ushort4 h4, l4;
        if (row < rows) {
            float4 v = *(const float4*)(src + (size_t)row * cols + c);
            split_hl(v.x, h4.x, l4.x); split_hl(v.y, h4.y, l4.y);
            split_hl(v.z, h4.z, l4.z); split_hl(v.w, h4.w, l4.w);
        } else {
            h4 = make_ushort4(0,0,0,0); l4 = h4;
        }
        *(ushort4*)(ph + (size_t)row * cols + c) = h4;
        *(ushort4*)(pl + (size_t)row * cols + c) = l4;
    }
}

// hi-only split (for logits B plane)
__global__ void split_rows_hi_k(const float* __restrict__ src, ushort* __restrict__ ph,
                                int rows, int cols) {
    int row = blockIdx.x;
    for (int c = threadIdx.x * 4; c < cols; c += blockDim.x * 4) {
        ushort4 h4;
        if (row < rows) {
            float4 v = *(const float4*)(src + (size_t)row * cols + c);
            h4.x = bf16_rne(v.x); h4.y = bf16_rne(v.y);
            h4.z = bf16_rne(v.z); h4.w = bf16_rne(v.w);
        } else {
            h4 = make_ushort4(0,0,0,0);
        }
        *(ushort4*)(ph + (size_t)row * cols + c) = h4;
    }
}

// ---------------- RMSNorm, fp32 out (fallback) ----------------
__global__ void rmsnorm_k(const float* __restrict__ x, const float* __restrict__ w,
                          float* __restrict__ out) {
    int l = blockIdx.x;
    const float4* xr = (const float4*)(x + (size_t)l * DMODEL);
    float4 v = xr[threadIdx.x];
    float ss = v.x*v.x + v.y*v.y + v.z*v.z + v.w*v.w;
    for (int off = 32; off > 0; off >>= 1) ss += __shfl_down(ss, off, 64);
    __shared__ float sred[4];
    int wid = threadIdx.x >> 6;
    if ((threadIdx.x & 63) == 0) sred[wid] = ss;
    __syncthreads();
    float tot = sred[0] + sred[1] + sred[2] + sred[3];
    float scale = rsqrtf(tot * (1.0f / DMODEL) + 1e-5f);
    float4 wv = ((const float4*)w)[threadIdx.x];
    float4 o;
    o.x = v.x * scale * wv.x; o.y = v.y * scale * wv.y;
    o.z = v.z * scale * wv.z; o.w = v.w * scale * wv.w;
    ((float4*)(out + (size_t)l * DMODEL))[threadIdx.x] = o;
}

// ---------------- RMSNorm -> hi/lo bf16 planes ----------------
__global__ void rmsnorm_hl_k(const float* __restrict__ x, const float* __restrict__ w,
                             ushort* __restrict__ hh, ushort* __restrict__ hl) {
    int l = blockIdx.x;
    const float4* xr = (const float4*)(x + (size_t)l * DMODEL);
    float4 v = xr[threadIdx.x];
    float ss = v.x*v.x + v.y*v.y + v.z*v.z + v.w*v.w;
    for (int off = 32; off > 0; off >>= 1) ss += __shfl_down(ss, off, 64);
    __shared__ float sred[4];
    int wid = threadIdx.x >> 6;
    if ((threadIdx.x & 63) == 0) sred[wid] = ss;
    __syncthreads();
    float tot = sred[0] + sred[1] + sred[2] + sred[3];
    float scale = rsqrtf(tot * (1.0f / DMODEL) + 1e-5f);
    float4 wv = ((const float4*)w)[threadIdx.x];
    float4 o;
    o.x = v.x * scale * wv.x; o.y = v.y * scale * wv.y;
    o.z = v.z * scale * wv.z; o.w = v.w * scale * wv.w;
    ushort4 h4, l4;
    split_hl(o.x, h4.x, l4.x); split_hl(o.y, h4.y, l4.y);
    split_hl(o.z, h4.z, l4.z); split_hl(o.w, h4.w, l4.w);
    *(ushort4*)(hh + (size_t)l * DMODEL + threadIdx.x * 4) = h4;
    *(ushort4*)(hl + (size_t)l * DMODEL + threadIdx.x * 4) = l4;
}

// ---------------- causal depthwise conv (k=4) + silu ----------------
__global__ void conv_silu_k(const float* __restrict__ XR, const float* __restrict__ w,
                            const float* __restrict__ b, float* __restrict__ out) {
    int idx = blockIdx.x * blockDim.x + threadIdx.x;
    int d = idx & (DINNER - 1);
    int l = idx >> 11;
    float4 wv = *(const float4*)(w + (size_t)d * 4);
    float acc = b[d];
    const float* col = XR + d;
    if (l >= 3) {
        acc += wv.x * col[(size_t)(l-3) * (2*DINNER)];
        acc += wv.y * col[(size_t)(l-2) * (2*DINNER)];
        acc += wv.z * col[(size_t)(l-1) * (2*DINNER)];
    } else {
        if (l-3 >= 0) acc += wv.x * col[(size_t)(l-3) * (2*DINNER)];
        if (l-2 >= 0) acc += wv.y * col[(size_t)(l-2) * (2*DINNER)];
        if (l-1 >= 0) acc += wv.z * col[(size_t)(l-1) * (2*DINNER)];
    }
    acc += wv.w * col[(size_t)l * (2*DINNER)];
    out[(size_t)l * DINNER + d] = silu_f(acc);
}

// ---------------- fp32 GEMM (small K / small N cases) ----------------
template<int EPI, bool BNC>
__global__ __launch_bounds__(256) void gemm_bt_k(
    const float* __restrict__ A, const float* __restrict__ B, float* __restrict__ C,
    int M, int N, int K, int lda, int ldb, int ldc, const float* __restrict__ E)
{
    __shared__ float As[16][68];
    __shared__ float Bs[16][68];
    int m0 = blockIdx.y * 64;
    int n0 = blockIdx.x * 64;
    int t = threadIdx.x;
    int tx = t & 15, ty = t >> 4;
    int lrow = t >> 2;
    int lc = (t & 3) * 4;
    float acc[4][4] = {};

    for (int k0 = 0; k0 < K; k0 += 16) {
        float4 a4 = *(const float4*)(A + (size_t)(m0 + lrow) * lda + k0 + lc);
        As[lc + 0][lrow] = a4.x; As[lc + 1][lrow] = a4.y;
        As[lc + 2][lrow] = a4.z; As[lc + 3][lrow] = a4.w;
        float4 b4;
        if (BNC && (n0 + lrow >= N)) b4 = make_float4(0.f, 0.f, 0.f, 0.f);
        else b4 = *(const float4*)(B + (size_t)(n0 + lrow) * ldb + k0 + lc);
        Bs[lc + 0][lrow] = b4.x; Bs[lc + 1][lrow] = b4.y;
        Bs[lc + 2][lrow] = b4.z; Bs[lc + 3][lrow] = b4.w;
        __syncthreads();
#pragma unroll
        for (int k = 0; k < 16; ++k) {
            float4 av = *(const float4*)(&As[k][ty * 4]);
            float4 bv = *(const float4*)(&Bs[k][tx * 4]);
            acc[0][0] += av.x * bv.x; acc[0][1] += av.x * bv.y;
            acc[0][2] += av.x * bv.z; acc[0][3] += av.x * bv.w;
            acc[1][0] += av.y * bv.x; acc[1][1] += av.y * bv.y;
            acc[1][2] += av.y * bv.z; acc[1][3] += av.y * bv.w;
            acc[2][0] += av.z * bv.x; acc[2][1] += av.z * bv.y;
            acc[2][2] += av.z * bv.z; acc[2][3] += av.z * bv.w;
            acc[3][0] += av.w * bv.x; acc[3][1] += av.w * bv.y;
            acc[3][2] += av.w * bv.z; acc[3][3] += av.w * bv.w;
        }
        __syncthreads();
    }

    int n = n0 + tx * 4;
    if (BNC && n >= N) return;
#pragma unroll
    for (int i = 0; i < 4; ++i) {
        int m = m0 + ty * 4 + i;
        float4 r;
        r.x = acc[i][0]; r.y = acc[i][1]; r.z = acc[i][2]; r.w = acc[i][3];
        if (EPI == 2) {
            float4 bb = *(const float4*)(E + n);
            r.x = sp_softplus(r.x + bb.x); r.y = sp_softplus(r.y + bb.y);
            r.z = sp_softplus(r.z + bb.z); r.w = sp_softplus(r.w + bb.w);
        }
        *(float4*)(C + (size_t)m * ldc + n) = r;
    }
}

// ============ pre-split plane MFMA GEMM (round-1 proven structure) ============
// C[M,N] = A @ B^T from bf16 hi/lo planes. BM=128, BN=32*NT, BK=32.
// NPROD=3: ah*bh + al*bh + ah*bl.  NPROD=2: ah*bh + al*bh (Bl unused, pass null).
// Reg-staged LDS ([rows][40] padded layout, identical to round-1 gemm_mfma_k).
// Requires M%128==0, N%BN==0 on the PLANES (pad B planes), K%32==0.
// EPI: 0 = store, 1 = store + E (residual). BNC guards only the C store.
template<int NT, int NPROD, int EPI, bool BNC>
__global__ __launch_bounds__(256, 3) void gemm_ps_k(
    const ushort* __restrict__ Ah, const ushort* __restrict__ Al,
    const ushort* __restrict__ Bh, const ushort* __restrict__ Bl,
    float* __restrict__ C, int M, int N, int K, int ldc,
    const float* __restrict__ E)
{
    constexpr int BN = 32 * NT;
    __shared__ alignas(16) ushort AhS[128][40];
    __shared__ alignas(16) ushort AlS[128][40];
    __shared__ alignas(16) ushort BhS[BN][40];
    __shared__ alignas(16) ushort BlS[(NPROD == 3) ? BN : 1][40];

    const int t    = threadIdx.x;
    const int lane = t & 63;
    const int wave = t >> 6;
    const int m0   = blockIdx.y * 128;
    const int n0   = blockIdx.x * BN;
    const int wm   = (wave >> 1) * 64;        // wave quadrant rows (4 frags)
    const int wn   = (wave & 1) * (BN / 2);   // wave quadrant cols (NT frags)
    const int fr   = lane & 15;
    const int kg   = (lane >> 4) * 8;
    const int lrow = t >> 2;                  // staging row 0..63
    const int lk   = (t & 3) * 8;             // staging ushort col {0,8,16,24}

    const f32x4 zero = {0.f, 0.f, 0.f, 0.f};
    f32x4 acc[4][NT];
#pragma unroll
    for (int i = 0; i < 4; ++i)
#pragma unroll
        for (int j = 0; j < NT; ++j) acc[i][j] = zero;

    for (int k0 = 0; k0 < K; k0 += 32) {
        // ---- stage A planes (128 rows) ----
#pragma unroll
        for (int i = 0; i < 2; ++i) {
            int r = lrow + i * 64;
            *(float4*)&AhS[r][lk] = *(const float4*)(Ah + (size_t)(m0 + r) * K + k0 + lk);
            *(float4*)&AlS[r][lk] = *(const float4*)(Al + (size_t)(m0 + r) * K + k0 + lk);
        }
        // ---- stage B planes (BN rows; planes pre-padded, no guard) ----
#pragma unroll
        for (int i = 0; i < BN / 64; ++i) {
            int r = lrow + i * 64;
            *(float4*)&BhS[r][lk] = *(const float4*)(Bh + (size_t)(n0 + r) * K + k0 + lk);
            if (NPROD == 3)
                *(float4*)&BlS[r][lk] = *(const float4*)(Bl + (size_t)(n0 + r) * K + k0 + lk);
        }
        __syncthreads();

        bf16x8 ah[4], al[4];
#pragma unroll
        for (int mt = 0; mt < 4; ++mt) {
            ah[mt] = *(const bf16x8*)&AhS[wm + mt * 16 + fr][kg];
            al[mt] = *(const bf16x8*)&AlS[wm + mt * 16 + fr][kg];
        }
#pragma unroll
        for (int nt = 0; nt < NT; ++nt) {
            bf16x8 bh = *(const bf16x8*)&BhS[wn + nt * 16 + fr][kg];
#pragma unroll
            for (int mt = 0; mt < 4; ++mt)
                acc[mt][nt] = __builtin_amdgcn_mfma_f32_16x16x32_bf16(ah[mt], bh, acc[mt][nt], 0, 0, 0);
#pragma unroll
            for (int mt = 0; mt < 4; ++mt)
                acc[mt][nt] = __builtin_amdgcn_mfma_f32_16x16x32_bf16(al[mt], bh, acc[mt][nt], 0, 0, 0);
            if (NPROD == 3) {
                bf16x8 bl = *(const bf16x8*)&BlS[wn + nt * 16 + fr][kg];
#pragma unroll
                for (int mt = 0; mt < 4; ++mt)
                    acc[mt][nt] = __builtin_amdgcn_mfma_f32_16x16x32_bf16(ah[mt], bl, acc[mt][nt], 0, 0, 0);
            }
        }
        __syncthreads();
    }

    // epilogue: C/D layout col = lane&15, row = (lane>>4)*4 + reg
    const int rq = (lane >> 4) * 4;
#pragma unroll
    for (int nt = 0; nt < NT; ++nt) {
        int n = n0 + wn + nt * 16 + fr;
        if (BNC && n >= N) continue;
#pragma unroll
        for (int mt = 0; mt < 4; ++mt) {
            int mb = m0 + wm + mt * 16 + rq;
#pragma unroll
            for (int r = 0; r < 4; ++r) {
                float v = acc[mt][nt][r];
                if (EPI == 1) v += E[(size_t)(mb + r) * ldc + n];
                C[(size_t)(mb + r) * ldc + n] = v;
            }
        }
    }
}

// ---------------- OLD in-kernel-split MFMA GEMM (fallback path) ----------------
template<int EPI, bool BNC>
__global__ __launch_bounds__(256, 3) void gemm_mfma_k(
    const float* __restrict__ A, const float* __restrict__ B, float* __restrict__ C,
    int M, int N, int K, int lda, int ldb, int ldc, const float* __restrict__ E)
{
    __shared__ alignas(16) ushort Ah[128][40];
    __shared__ alignas(16) ushort Al[128][40];
    __shared__ alignas(16) ushort Bh[128][40];
    __shared__ alignas(16) ushort Bl[128][40];

    const int t    = threadIdx.x;
    const int lane = t & 63;
    const int wave = t >> 6;
    const int wm   = (wave >> 1) * 64;
    const int wn   = (wave & 1) * 64;
    const int m0   = blockIdx.y * 128;
    const int n0   = blockIdx.x * 128;
    const int lrow = t >> 3;
    const int lk   = (t & 7) * 4;
    const int fr   = lane & 15;
    const int kg   = (lane >> 4) * 8;

    const f32x4 zero = {0.f, 0.f, 0.f, 0.f};
    f32x4 acc[4][4];
#pragma unroll
    for (int i = 0; i < 4; ++i)
#pragma unroll
        for (int j = 0; j < 4; ++j) acc[i][j] = zero;

    for (int k0 = 0; k0 < K; k0 += 32) {
#pragma unroll
        for (int i = 0; i < 4; ++i) {
            int r = lrow + i * 32;
            float4 a4 = *(const float4*)(A + (size_t)(m0 + r) * lda + k0 + lk);
            split_store4(&Ah[r][lk], &Al[r][lk], a4);
            float4 b4;
            if (BNC && (n0 + r >= N)) b4 = make_float4(0.f, 0.f, 0.f, 0.f);
            else b4 = *(const float4*)(B + (size_t)(n0 + r) * ldb + k0 + lk);
            split_store4(&Bh[r][lk], &Bl[r][lk], b4);
        }
        __syncthreads();

        bf16x8 ah[4], al[4];
#pragma unroll
        for (int mt = 0; mt < 4; ++mt) {
            ah[mt] = *(const bf16x8*)&Ah[wm + mt * 16 + fr][kg];
            al[mt] = *(const bf16x8*)&Al[wm + mt * 16 + fr][kg];
        }
#pragma unroll
        for (int nt = 0; nt < 4; ++nt) {
            bf16x8 bh = *(const bf16x8*)&Bh[wn + nt * 16 + fr][kg];
            bf16x8 bl = *(const bf16x8*)&Bl[wn + nt * 16 + fr][kg];
#pragma unroll
            for (int mt = 0; mt < 4; ++mt) {
                acc[mt][nt] = __builtin_amdgcn_mfma_f32_16x16x32_bf16(ah[mt], bh, acc[mt][nt], 0, 0, 0);
                acc[mt][nt] = __builtin_amdgcn_mfma_f32_16x16x32_bf16(al[mt], bh, acc[mt][nt], 0, 0, 0);
                acc[mt][nt] = __builtin_amdgcn_mfma_f32_16x16x32_bf16(ah[mt], bl, acc[mt][nt], 0, 0, 0);
            }
        }
        __syncthreads();
    }

    const int rq = (lane >> 4) * 4;
#pragma unroll
    for (int nt = 0; nt < 4; ++nt) {
        int n = n0 + wn + nt * 16 + fr;
        if (BNC && n >= N) continue;
#pragma unroll
        for (int mt = 0; mt < 4; ++mt) {
            int mb = m0 + wm + mt * 16 + rq;
#pragma unroll
            for (int r = 0; r < 4; ++r) {
                float v = acc[mt][nt][r];
                if (EPI == 1) v += E[(size_t)(mb + r) * ldc + n];
                C[(size_t)(mb + r) * ldc + n] = v;
            }
        }
    }
}

// ---------------- selective scan (fallback, fp32 yz out) ----------------
__global__ __launch_bounds__(256) void scan_k(
    const float* __restrict__ delta, const float* __restrict__ u,
    const float* __restrict__ xdbl, const float* __restrict__ A_log,
    const float* __restrict__ Dp, const float* __restrict__ XR,
    float* __restrict__ yz)
{
    const int CH = 64;
    int d0 = blockIdx.x * 16;
    int t = threadIdx.x;
    int ci = t >> 4;
    int n  = t & 15;
    int d  = d0 + ci;
    float Av = -__expf(A_log[(size_t)d * DSTATE + n]);
    float Dv = Dp[d];
    float h = 0.f;

    __shared__ alignas(16) float sdel[CH][16];
    __shared__ alignas(16) float su[CH][16];
    __shared__ alignas(16) float sres[CH][16];
    __shared__ alignas(16) float sBC[CH][32];

    for (int l0 = 0; l0 < LSEQ; l0 += CH) {
        {
            int r = t >> 2, c = (t & 3) * 4;
            *(float4*)&sdel[r][c] = *(const float4*)(delta + (size_t)(l0 + r) * DINNER + d0 + c);
            *(float4*)&su[r][c]   = *(const float4*)(u     + (size_t)(l0 + r) * DINNER + d0 + c);
            *(float4*)&sres[r][c] = *(const float4*)(XR + (size_t)(l0 + r) * (2*DINNER) + DINNER + d0 + c);
        }
        for (int qq = t; qq < CH * 8; qq += 256) {
            int r = qq >> 3, c = (qq & 7) * 4;
            *(float4*)&sBC[r][c] = *(const float4*)(xdbl + (size_t)(l0 + r) * 96 + DTRANK + c);
        }
        __syncthreads();
#pragma unroll 4
        for (int r = 0; r < CH; ++r) {
            float dl = sdel[r][ci];
            float uv = su[r][ci];
            float Bv = sBC[r][n];
            float Cv = sBC[r][16 + n];
            float dA = __expf(dl * Av);
            h = dA * h + dl * uv * Bv;
            float p = h * Cv;
            p += __shfl_xor(p, 1, 64);
            p += __shfl_xor(p, 2, 64);
            p += __shfl_xor(p, 4, 64);
            p += __shfl_xor(p, 8, 64);
            if (n == 0) {
                float y = p + uv * Dv;
                yz[(size_t)(l0 + r) * DINNER + d] = y * silu_f(sres[r][ci]);
            }
        }
        __syncthreads();
    }
}

// ---------------- selective scan: transposed LDS, 4-step batches, hi/lo out ----
__global__ __launch_bounds__(256) void scan2_k(
    const float* __restrict__ delta, const float* __restrict__ u,
    const float* __restrict__ xdbl, const float* __restrict__ A_log,
    const float* __restrict__ Dp, const float* __restrict__ XR,
    ushort* __restrict__ yzh, ushort* __restrict__ yzl)
{
    const int CH = 64;
    int d0 = blockIdx.x * 16;
    int t = threadIdx.x;
    int ci = t >> 4;           // channel 0..15
    int n  = t & 15;           // state 0..15
    int d  = d0 + ci;
    float Av = -__expf(A_log[(size_t)d * DSTATE + n]);
    float Dv = Dp[d];
    float h = 0.f;

    // transposed: [channel-or-state][timestep], +4 pad
    __shared__ alignas(16) float sdel[16][68], su[16][68], sres[16][68], sB[16][68], sC[16][68];

    const int rA = t >> 2;           // staging timestep 0..63
    const int cA = (t & 3) * 4;      // staging channel group
    const int jB = t & 3;            // staging n group for B/C

    for (int l0 = 0; l0 < LSEQ; l0 += CH) {
        {
            float4 dv = *(const float4*)(delta + (size_t)(l0 + rA) * DINNER + d0 + cA);
            float4 uv = *(const float4*)(u     + (size_t)(l0 + rA) * DINNER + d0 + cA);
            float4 rv = *(const float4*)(XR + (size_t)(l0 + rA) * (2*DINNER) + DINNER + d0 + cA);
            sdel[cA+0][rA] = dv.x; sdel[cA+1][rA] = dv.y; sdel[cA+2][rA] = dv.z; sdel[cA+3][rA] = dv.w;
            su  [cA+0][rA] = uv.x; su  [cA+1][rA] = uv.y; su  [cA+2][rA] = uv.z; su  [cA+3][rA] = uv.w;
            sres[cA+0][rA] = rv.x; sres[cA+1][rA] = rv.y; sres[cA+2][rA] = rv.z; sres[cA+3][rA] = rv.w;
            float4 bv = *(const float4*)(xdbl + (size_t)(l0 + rA) * 96 + DTRANK + jB * 4);
            float4 cv = *(const float4*)(xdbl + (size_t)(l0 + rA) * 96 + DTRANK + 16 + jB * 4);
            sB[jB*4+0][rA] = bv.x; sB[jB*4+1][rA] = bv.y; sB[jB*4+2][rA] = bv.z; sB[jB*4+3][rA] = bv.w;
            sC[jB*4+0][rA] = cv.x; sC[jB*4+1][rA] = cv.y; sC[jB*4+2][rA] = cv.z; sC[jB*4+3][rA] = cv.w;
        }
        __syncthreads();
        for (int r4 = 0; r4 < CH; r4 += 4) {
            float4 dl4 = *(const float4*)&sdel[ci][r4];
            float4 uu4 = *(const float4*)&su[ci][r4];
            float4 bb4 = *(const float4*)&sB[n][r4];
            float4 cc4 = *(const float4*)&sC[n][r4];
            float e0 = __expf(dl4.x * Av), e1 = __expf(dl4.y * Av);
            float e2 = __expf(dl4.z * Av), e3 = __expf(dl4.w * Av);
            float p0, p1, p2, p3;
            h = e0 * h + dl4.x * uu4.x * bb4.x; p0 = h * cc4.x;
            h = e1 * h + dl4.y * uu4.y * bb4.y; p1 = h * cc4.y;
            h = e2 * h + dl4.z * uu4.z * bb4.z; p2 = h * cc4.z;
            h = e3 * h + dl4.w * uu4.w * bb4.w; p3 = h * cc4.w;
            // 4 interleaved butterfly reductions over the 16 state lanes
            p0 += __shfl_xor(p0, 1, 64); p1 += __shfl_xor(p1, 1, 64);
            p2 += __shfl_xor(p2, 1, 64); p3 += __shfl_xor(p3, 1, 64);
            p0 += __shfl_xor(p0, 2, 64); p1 += __shfl_xor(p1, 2, 64);
            p2 += __shfl_xor(p2, 2, 64); p3 += __shfl_xor(p3, 2, 64);
            p0 += __shfl_xor(p0, 4, 64); p1 += __shfl_xor(p1, 4, 64);
            p2 += __shfl_xor(p2, 4, 64); p3 += __shfl_xor(p3, 4, 64);
            p0 += __shfl_xor(p0, 8, 64); p1 += __shfl_xor(p1, 8, 64);
            p2 += __shfl_xor(p2, 8, 64); p3 += __shfl_xor(p3, 8, 64);
            if (n == 0) {
                float4 rs4 = *(const float4*)&sres[ci][r4];
                float y0 = (p0 + uu4.x * Dv) * silu_f(rs4.x);
                float y1 = (p1 + uu4.y * Dv) * silu_f(rs4.y);
                float y2 = (p2 + uu4.z * Dv) * silu_f(rs4.z);
                float y3 = (p3 + uu4.w * Dv) * silu_f(rs4.w);
                size_t base = (size_t)(l0 + r4) * DINNER + d;
                ushort hh_, ll_;
                split_hl(y0, hh_, ll_); yzh[base]            = hh_; yzl[base]            = ll_;
                split_hl(y1, hh_, ll_); yzh[base +   DINNER] = hh_; yzl[base +   DINNER] = ll_;
                split_hl(y2, hh_, ll_); yzh[base + 2*DINNER] = hh_; yzl[base + 2*DINNER] = ll_;
                split_hl(y3, hh_, ll_); yzh[base + 3*DINNER] = hh_; yzl[base + 3*DINNER] = ll_;
            }
        }
        __syncthreads();
    }
}

extern "C" void kernel_launch(void* const* d_in, const int* in_sizes, int n_in,
                              void* d_out, int out_size, void* d_ws, size_t ws_size,
                              hipStream_t stream) {
    const int*   ids    = (const int*)  d_in[0];
    const float* emb    = (const float*)d_in[1];
    const float* in_w   = (const float*)d_in[2];   // [2,4096,1024]
    const float* conv_w = (const float*)d_in[3];   // [2,2048,1,4]
    const float* conv_b = (const float*)d_in[4];   // [2,2048]
    const float* xp_w   = (const float*)d_in[5];   // [2,96,2048]
    const float* dt_w   = (const float*)d_in[6];   // [2,2048,64]
    const float* dt_b   = (const float*)d_in[7];   // [2,2048]
    const float* A_log  = (const float*)d_in[8];   // [2,2048,16]
    const float* Dp     = (const float*)d_in[9];   // [2,2048]
    const float* out_w  = (const float*)d_in[10];  // [2,1024,2048]
    const float* nw     = (const float*)d_in[11];  // [2,1024]
    const float* nfw    = (const float*)d_in[12];  // [1024]
    float* out = (float*)d_out;

    // ---- workspace carve-up (fast path) ----
    char* base = (char*)d_ws;
    size_t off = 0;
    auto carve = [&](size_t bytes) { char* p = base + off; off += (bytes + 255) & ~(size_t)255; return p; };
    float*  x     = (float*) carve((size_t)LSEQ * DMODEL * 4);
    float*  XR    = (float*) carve((size_t)LSEQ * 2 * DINNER * 4);
    float*  xconv = (float*) carve((size_t)LSEQ * DINNER * 4);
    float*  xdbl  = (float*) carve((size_t)LSEQ * 96 * 4);
    float*  delta = (float*) carve((size_t)LSEQ * DINNER * 4);
    ushort* hh    = (ushort*)carve((size_t)LSEQ * DMODEL * 2);
    ushort* hl    = (ushort*)carve((size_t)LSEQ * DMODEL * 2);
    ushort* yzh   = (ushort*)carve((size_t)LSEQ * DINNER * 2);
    ushort* yzl   = (ushort*)carve((size_t)LSEQ * DINNER * 2);
    ushort* inwh  = (ushort*)carve((size_t)(2*DINNER) * DMODEL * 2);
    ushort* inwl  = (ushort*)carve((size_t)(2*DINNER) * DMODEL * 2);
    ushort* outwh = (ushort*)carve((size_t)DMODEL * DINNER * 2);
    ushort* outwl = (ushort*)carve((size_t)DMODEL * DINNER * 2);
    ushort* embh  = (ushort*)carve((size_t)NVPAD * DMODEL * 2);
    const size_t NEED = off;

    if (ws_size >= NEED) {
        // ================= fast path: pre-split planes =================
        embed_k<<<LSEQ, 256, 0, stream>>>(ids, emb, x);
        split_rows_hi_k<<<NVPAD, 256, 0, stream>>>(emb, embh, NVOCAB, DMODEL);

        for (int i = 0; i < 2; ++i) {
            split_rows_k<<<2*DINNER, 256, 0, stream>>>(
                in_w + (size_t)i * 2*DINNER * DMODEL, inwh, inwl, 2*DINNER, DMODEL);
            split_rows_k<<<DMODEL, 256, 0, stream>>>(
                out_w + (size_t)i * DMODEL * DINNER, outwh, outwl, DMODEL, DINNER);

            rmsnorm_hl_k<<<LSEQ, 256, 0, stream>>>(x, nw + (size_t)i * DMODEL, hh, hl);
            // in_proj: [L,1024]@[4096,1024]^T -> XR (3-product, BN=128)
            gemm_ps_k<4,3,0,false><<<dim3(4096/128, LSEQ/128), 256, 0, stream>>>(
                hh, hl, inwh, inwl, XR, LSEQ, 2*DINNER, DMODEL, 2*DINNER, nullptr);
            conv_silu_k<<<(LSEQ * DINNER) / 256, 256, 0, stream>>>(
                XR, conv_w + (size_t)i * DINNER * 4, conv_b + (size_t)i * DINNER, xconv);
            gemm_bt_k<0, true><<<dim3(2, LSEQ/64), 256, 0, stream>>>(
                xconv, xp_w + (size_t)i * 96 * DINNER, xdbl,
                LSEQ, 96, DINNER, DINNER, DINNER, 96, nullptr);
            gemm_bt_k<2, false><<<dim3(DINNER/64, LSEQ/64), 256, 0, stream>>>(
                xdbl, dt_w + (size_t)i * DINNER * DTRANK, delta,
                LSEQ, DINNER, DTRANK, 96, DTRANK, DINNER, dt_b + (size_t)i * DINNER);
            scan2_k<<<DINNER/16, 256, 0, stream>>>(
                delta, xconv, xdbl, A_log + (size_t)i * DINNER * DSTATE,
                Dp + (size_t)i * DINNER, XR, yzh, yzl);
            // out_proj + residual: [L,2048]@[1024,2048]^T + x -> x (3-product, BN=64)
            gemm_ps_k<2,3,1,false><<<dim3(DMODEL/64, LSEQ/128), 256, 0, stream>>>(
                yzh, yzl, outwh, outwl, x, LSEQ, DMODEL, DINNER, DMODEL, x);
        }

        rmsnorm_hl_k<<<LSEQ, 256, 0, stream>>>(x, nfw, hh, hl);
        // logits: [L,1024]@[50264,1024]^T (2-product: B hi-only)
        gemm_ps_k<4,2,0,true><<<dim3(NVPAD/128, LSEQ/128), 256, 0, stream>>>(
            hh, hl, embh, (const ushort*)nullptr, out, LSEQ, NVOCAB, DMODEL, NVOCAB, nullptr);
    } else {
        // ================= fallback: round-1 path (proven) =================
        float* ws    = (float*)d_ws;
        float* xx    = ws;
        float* hbuf  = xx    + (size_t)LSEQ * DMODEL;
        float* XRf   = hbuf  + (size_t)LSEQ * DMODEL;
        float* xcv   = XRf   + (size_t)LSEQ * 2 * DINNER;
        float* xdb   = xcv   + (size_t)LSEQ * DINNER;
        float* dlt   = xdb   + (size_t)LSEQ * 96;
        float* yzf   = dlt   + (size_t)LSEQ * DINNER;

        embed_k<<<LSEQ, 256, 0, stream>>>(ids, emb, xx);
        for (int i = 0; i < 2; ++i) {
            rmsnorm_k<<<LSEQ, 256, 0, stream>>>(xx, nw + (size_t)i * DMODEL, hbuf);
            gemm_mfma_k<0, false><<<dim3(4096/128, LSEQ/128), 256, 0, stream>>>(
                hbuf, in_w + (size_t)i * 2*DINNER * DMODEL, XRf,
                LSEQ, 2*DINNER, DMODEL, DMODEL, DMODEL, 2*DINNER, nullptr);
            conv_silu_k<<<(LSEQ * DINNER) / 256, 256, 0, stream>>>(
                XRf, conv_w + (size_t)i * DINNER * 4, conv_b + (size_t)i * DINNER, xcv);
            gemm_bt_k<0, true><<<dim3(2, LSEQ/64), 256, 0, stream>>>(
                xcv, xp_w + (size_t)i * 96 * DINNER, xdb,
                LSEQ, 96, DINNER, DINNER, DINNER, 96, nullptr);
            gemm_bt_k<2, false><<<dim3(DINNER/64, LSEQ/64), 256, 0, stream>>>(
                xdb, dt_w + (size_t)i * DINNER * DTRANK, dlt,
                LSEQ, DINNER, DTRANK, 96, DTRANK, DINNER, dt_b + (size_t)i * DINNER);
            scan_k<<<DINNER/16, 256, 0, stream>>>(
                dlt, xcv, xdb, A_log + (size_t)i * DINNER * DSTATE,
                Dp + (size_t)i * DINNER, XRf, yzf);
            gemm_mfma_k<1, false><<<dim3(DMODEL/128, LSEQ/128), 256, 0, stream>>>(
                yzf, out_w + (size_t)i * DMODEL * DINNER, xx,
                LSEQ, DMODEL, DINNER, DINNER, DINNER, DMODEL, xx);
        }
        rmsnorm_k<<<LSEQ, 256, 0, stream>>>(xx, nfw, hbuf);
        gemm_mfma_k<0, true><<<dim3((NVOCAB + 127) / 128, LSEQ/128), 256, 0, stream>>>(
            hbuf, emb, out, LSEQ, NVOCAB, DMODEL, DMODEL, DMODEL, NVOCAB, nullptr);
    }
}